// Round 6
// baseline (228.146 us; speedup 1.0000x reference)
//
#include <hip/hip_runtime.h>

#define B_ 4
#define T_ 2048
#define C_ 1024
#define H_ 16
#define D_ 64
#define M_ (B_*T_)    // 8192
#define N3_ (3*C_)    // 3072
#define NKT_ 32       // number of 64-row q-tiles (= T/64)

typedef unsigned short u16;
typedef short bf16x8 __attribute__((ext_vector_type(8)));
typedef short bf16x4 __attribute__((ext_vector_type(4)));
typedef unsigned short u16x8 __attribute__((ext_vector_type(8)));
typedef unsigned int u32x4 __attribute__((ext_vector_type(4)));
typedef float f32x4 __attribute__((ext_vector_type(4)));
typedef float f32x16 __attribute__((ext_vector_type(16)));

#define QSCALE 0.18033688f   /* 0.125 * log2(e): softmax done in exp2 domain */
#define DEFER_THR 11.0f      /* defer-max threshold in log2 units (~8 nats) */

__device__ __forceinline__ u16 f2bf(float f) {
  unsigned u = __float_as_uint(f);
  u += 0x7fffu + ((u >> 16) & 1u);
  return (u16)(u >> 16);
}
__device__ __forceinline__ float bf2f(u16 u) { return __uint_as_float(((unsigned)u) << 16); }

__device__ __forceinline__ unsigned cvt_pk_bf16(float lo, float hi) {
  unsigned r;
  asm("v_cvt_pk_bf16_f32 %0, %1, %2" : "=v"(r) : "v"(lo), "v"(hi));
  return r;
}

__device__ __forceinline__ void gload16(const void* g, void* l) {
  __builtin_amdgcn_global_load_lds((const __attribute__((address_space(1))) void*)g,
                                   (__attribute__((address_space(3))) void*)l, 16, 0, 0);
}

// ---------------- elementwise f32 -> bf16 ----------------
__global__ __launch_bounds__(256) void k_convert(const float* __restrict__ in,
                                                 u16* __restrict__ out, int n8) {
  int i = blockIdx.x * 256 + threadIdx.x;
  if (i >= n8) return;
  f32x4 a = *(const f32x4*)(in + (size_t)i * 8);
  f32x4 b = *(const f32x4*)(in + (size_t)i * 8 + 4);
  u16x8 o;
  #pragma unroll
  for (int j = 0; j < 4; ++j) { o[j] = f2bf(a[j]); o[4 + j] = f2bf(b[j]); }
  *(u16x8*)(out + (size_t)i * 8) = o;
}

// ---------------- transpose+convert: W [K][N] f32 -> Wt [N][K] bf16 ----------------
__global__ __launch_bounds__(256) void k_transpose(const float* __restrict__ W,
                                                   u16* __restrict__ Wt, int K, int N) {
  __shared__ float tile[64][65];
  int n0 = blockIdx.x * 64, k0 = blockIdx.y * 64;
  int c = threadIdx.x & 63, r0 = threadIdx.x >> 6;
  #pragma unroll
  for (int i = 0; i < 16; ++i) {
    int r = i * 4 + r0;
    tile[r][c] = W[(size_t)(k0 + r) * N + n0 + c];
  }
  __syncthreads();
  #pragma unroll
  for (int i = 0; i < 16; ++i) {
    int r = i * 4 + r0;
    Wt[(size_t)(n0 + r) * K + k0 + c] = f2bf(tile[c][r]);
  }
}

// ---------------- RoPE cos/sin tables (double precision on device) ----------------
__global__ void k_rope_table(float* __restrict__ ct, float* __restrict__ st) {
  int idx = blockIdx.x * 256 + threadIdx.x;   // T_*32 entries
  int t = idx >> 5, i = idx & 31;
  double inv = exp(-(2.0 * (double)i / 64.0) * log(10000.0));
  double a = (double)t * inv;
  ct[idx] = (float)cos(a);
  st[idx] = (float)sin(a);
}

// ---------------- V [B,H,T,D] bf16 -> Vt [B,H,D,T] bf16 ----------------
__global__ __launch_bounds__(256) void k_vtrans(const u16* __restrict__ V,
                                                u16* __restrict__ Vt) {
  __shared__ u16 tile[64][65];
  int t0 = blockIdx.x * 64;
  size_t bh = (size_t)blockIdx.z * H_ + blockIdx.y;
  const u16* src = V + (bh * T_ + t0) * D_;
  u16* dst = Vt + bh * (size_t)D_ * T_ + t0;
  int r0 = threadIdx.x >> 3, c0 = (threadIdx.x & 7) * 8;
  #pragma unroll
  for (int i = 0; i < 2; ++i) {
    int rr = i * 32 + r0;
    u16x8 v = *(const u16x8*)(src + rr * D_ + c0);
    #pragma unroll
    for (int j = 0; j < 8; ++j) tile[rr][c0 + j] = v[j];
  }
  __syncthreads();
  #pragma unroll
  for (int i = 0; i < 2; ++i) {
    int d = i * 32 + r0;
    u16x8 o;
    #pragma unroll
    for (int j = 0; j < 8; ++j) o[j] = tile[c0 + j][d];
    *(u16x8*)(dst + (size_t)d * T_ + c0) = o;
  }
}

// ---------------- bf16 GEMM: A[M][K] @ Bt[N][K]^T + bias ----------------
// 128x128 tile, BK=64, 4 waves. T3-minimum 2-phase: double-buffered LDS,
// STAGE(next) issued BEFORE compute(cur), ONE barrier per K-step (its
// implicit vmcnt(0) covers staged loads + buffer reuse). Pre-swizzled
// global source keeps ds_read_b128 conflict-free (T2).
// MODE 0: fused RoPE (Q pre-scaled by QSCALE), scatter Q/K/V [B,H,T,D] bf16.
// MODE 1: fp32 C[M][N].  XCD-aware block swizzle (grid size % 8 == 0).
template <int MODE>
__global__ __launch_bounds__(256) void k_gemm(const u16* __restrict__ A,
                                              const u16* __restrict__ Bt,
                                              const float* __restrict__ bias,
                                              float* __restrict__ Cout,
                                              u16* __restrict__ Qb, u16* __restrict__ Kb,
                                              u16* __restrict__ Vb,
                                              const float* __restrict__ ctab,
                                              const float* __restrict__ stab,
                                              int Md, int Nd, int Kd) {
  __shared__ u16 sA[2][128 * 64];
  __shared__ u16 sB[2][128 * 64];
  const int tid = threadIdx.x, lane = tid & 63, w = tid >> 6;
  const int g = lane >> 4, r = lane & 15;
  const int wm = w >> 1, wn = w & 1;
  // XCD swizzle: contiguous chunk of blocks per XCD
  const int gx = gridDim.x;
  const int lin = blockIdx.y * gx + blockIdx.x;
  const int cpx = (gx * gridDim.y) >> 3;
  const int swz = (lin & 7) * cpx + (lin >> 3);
  const int tM = (swz / gx) * 128, tN = (swz % gx) * 128;

  f32x4 acc[4][4];
  #pragma unroll
  for (int i = 0; i < 4; ++i)
    #pragma unroll
    for (int j = 0; j < 4; ++j) acc[i][j] = (f32x4){0.f, 0.f, 0.f, 0.f};

  auto STAGE = [&](int buf, int k0) {
    #pragma unroll
    for (int i = 0; i < 4; ++i) {
      int c = i * 256 + tid, row = c >> 3, slot = (c & 7) ^ (row & 7);
      gload16(A + (size_t)(tM + row) * Kd + k0 + slot * 8, &sA[buf][(i * 256 + w * 64) * 8]);
    }
    #pragma unroll
    for (int i = 0; i < 4; ++i) {
      int c = i * 256 + tid, row = c >> 3, slot = (c & 7) ^ (row & 7);
      gload16(Bt + (size_t)(tN + row) * Kd + k0 + slot * 8, &sB[buf][(i * 256 + w * 64) * 8]);
    }
  };

  STAGE(0, 0);
  __syncthreads();

  int cur = 0;
  for (int k0 = 0; k0 < Kd; k0 += 64) {
    if (k0 + 64 < Kd) STAGE(cur ^ 1, k0 + 64);   // prefetch next tile (hidden)
    bf16x8 af[4][2], bfr[4][2];
    #pragma unroll
    for (int mt = 0; mt < 4; ++mt)
      #pragma unroll
      for (int kk = 0; kk < 2; ++kk) {
        int row = wm * 64 + mt * 16 + r;
        af[mt][kk] = *(const bf16x8*)(&sA[cur][(row * 64 + kk * 32 + g * 8) ^ ((row & 7) << 3)]);
      }
    #pragma unroll
    for (int nt = 0; nt < 4; ++nt)
      #pragma unroll
      for (int kk = 0; kk < 2; ++kk) {
        int row = wn * 64 + nt * 16 + r;
        bfr[nt][kk] = *(const bf16x8*)(&sB[cur][(row * 64 + kk * 32 + g * 8) ^ ((row & 7) << 3)]);
      }
    __builtin_amdgcn_s_setprio(1);
    #pragma unroll
    for (int mt = 0; mt < 4; ++mt)
      #pragma unroll
      for (int nt = 0; nt < 4; ++nt)
        #pragma unroll
        for (int kk = 0; kk < 2; ++kk)
          acc[mt][nt] = __builtin_amdgcn_mfma_f32_16x16x32_bf16(af[mt][kk], bfr[nt][kk],
                                                                acc[mt][nt], 0, 0, 0);
    __builtin_amdgcn_s_setprio(0);
    __syncthreads();   // staged loads landed + cur buffer free
    cur ^= 1;
  }

  // epilogue: C/D layout col = lane&15, row = (lane>>4)*4 + reg
  #pragma unroll
  for (int mt = 0; mt < 4; ++mt)
    #pragma unroll
    for (int nt = 0; nt < 4; ++nt) {
      int n = tN + wn * 64 + nt * 16 + r;
      float bv = bias[n];
      if (MODE == 1) {
        #pragma unroll
        for (int reg = 0; reg < 4; ++reg) {
          int m = tM + wm * 64 + mt * 16 + g * 4 + reg;
          Cout[(size_t)m * Nd + n] = acc[mt][nt][reg] + bv;
        }
      } else {
        int sec = n >> 10, idx = n & 1023, hh = idx >> 6, dd = idx & 63;
        #pragma unroll
        for (int reg = 0; reg < 4; ++reg) {
          int m = tM + wm * 64 + mt * 16 + g * 4 + reg;
          int bb = m >> 11, tt = m & (T_ - 1);
          float v = acc[mt][nt][reg] + bv;
          if (sec < 2) {   // fused RoPE on Q,K (pairs = adjacent lanes, DPP shfl)
            float pv = __shfl_xor(v, 1);
            int pi = tt * 32 + (dd >> 1);
            float c = ctab[pi], sn = stab[pi];
            v = (dd & 1) ? (v * c + pv * sn) : (v * c - pv * sn);
            if (sec == 0) v *= QSCALE;   // fold softmax scale into Q
          }
          u16 val = f2bf(v);
          size_t off = ((size_t)(bb * H_ + hh) * T_ + tt) * D_ + dd;
          if (sec == 0) Qb[off] = val;
          else if (sec == 1) Kb[off] = val;
          else Vb[off] = val;   // row-major; transposed by k_vtrans afterwards
        }
      }
    }
}

// ---------------- causal flash attention, 32x32 MFMA, causal-paired ----------------
// Each block = 2 waves x 32 q = 64 q-rows, and processes TWO q-tiles:
// {pair, NKT-1-pair}. Work per block = (a+1)+(NKT-a) = NKT+1 KV-iters for
// every pair -> zero static imbalance. Swapped QK^T and swapped PV
// (O^T = V^T.P^T): each lane owns one q end-to-end, P stays in registers.
// exp2-domain softmax with defer-max; double-buffered staging; cross-half
// prefetch (no bubble).
__global__ __launch_bounds__(128) void k_attn(const u16* __restrict__ Qb,
                                              const u16* __restrict__ Kb,
                                              const u16* __restrict__ Vt,
                                              u16* __restrict__ Y) {
  __shared__ u16 sK[2][64 * 64];
  __shared__ u16 sV[2][64 * 64];
  const int tid = threadIdx.x, w = tid >> 6;          // 2 waves
  const int lane = tid & 63, col = lane & 31, hi = lane >> 5;
  const int pair = blockIdx.x;                        // 0..NKT/2-1
  const int h = blockIdx.y, b = blockIdx.z;
  const size_t bhK = ((size_t)b * H_ + h) * T_;
  const size_t bhV = ((size_t)b * H_ + h) * D_;

  const int qtA = pair, qtB = (NKT_ - 1) - pair;
  const int ntA = qtA + 1;                            // KV tiles for half A
  const int total = NKT_ + 1;                         // ntA + (qtB+1)

  auto STAGE = [&](int buf, int kt) {
    #pragma unroll
    for (int i = 0; i < 4; ++i) {
      int c = i * 128 + tid, row = c >> 3, slot = (c & 7) ^ (row & 7);
      gload16(Kb + (bhK + kt * 64 + row) * D_ + slot * 8, &sK[buf][(i * 128 + w * 64) * 8]);
    }
    #pragma unroll
    for (int i = 0; i < 4; ++i) {
      int c = i * 128 + tid, row = c >> 3, slot = (c & 7) ^ (row & 7);
      gload16(Vt + (bhV + row) * T_ + kt * 64 + slot * 8, &sV[buf][(i * 128 + w * 64) * 8]);
    }
  };

  int qw = qtA * 64 + w * 32;          // wave's q range: [qw, qw+32)
  int tq = qw + col;                   // this lane's q-row
  bf16x8 qf[4];
  #pragma unroll
  for (int c = 0; c < 4; ++c)
    qf[c] = *(const bf16x8*)(Qb + (bhK + tq) * D_ + c * 16 + hi * 8);

  float m_run = -3e38f, l_run = 0.f;
  f32x16 o0, o1;                       // O^T: col=q (own), rows d
  #pragma unroll
  for (int i = 0; i < 16; ++i) { o0[i] = 0.f; o1[i] = 0.f; }

  auto FINAL = [&]() {
    float lr = l_run + __shfl_xor(l_run, 32);
    float rl = 1.0f / lr;
    u16* yrow = Y + ((size_t)b * T_ + tq) * C_ + h * 64;
    #pragma unroll
    for (int dt = 0; dt < 2; ++dt)
      #pragma unroll
      for (int j = 0; j < 8; ++j) {
        float a0 = (dt ? o1[2 * j] : o0[2 * j]) * rl;
        float a1 = (dt ? o1[2 * j + 1] : o0[2 * j + 1]) * rl;
        int d = dt * 32 + 8 * (j >> 1) + 4 * hi + 2 * (j & 1);
        *(unsigned*)(yrow + d) = cvt_pk_bf16(a0, a1);
      }
  };

  STAGE(0, 0);
  __syncthreads();

  for (int it = 0; it < total; ++it) {
    const int cur = it & 1;
    if (it + 1 < total) {               // prefetch next tile (maybe next half's kt=0)
      int nit = it + 1;
      STAGE(cur ^ 1, nit < ntA ? nit : nit - ntA);
    }
    const int ktl = it < ntA ? it : it - ntA;
    const int kb = ktl * 64;
    if (kb <= qw + 31) {                           // wave has live keys here
      const bool act1 = (kb + 32 <= qw + 31);      // subtile 1 live?
      f32x16 s0, s1;
      #pragma unroll
      for (int i = 0; i < 16; ++i) { s0[i] = 0.f; s1[i] = 0.f; }

      // S^T = K·Q^T  (A rows = keys, B cols = q)
      __builtin_amdgcn_s_setprio(1);
      #pragma unroll
      for (int c = 0; c < 4; ++c) {
        int row = col;
        bf16x8 kf = *(const bf16x8*)(&sK[cur][(row * 64 + c * 16 + hi * 8) ^ ((row & 7) << 3)]);
        s0 = __builtin_amdgcn_mfma_f32_32x32x16_bf16(kf, qf[c], s0, 0, 0, 0);
      }
      if (act1) {
        #pragma unroll
        for (int c = 0; c < 4; ++c) {
          int row = 32 + col;
          bf16x8 kf = *(const bf16x8*)(&sK[cur][(row * 64 + c * 16 + hi * 8) ^ ((row & 7) << 3)]);
          s1 = __builtin_amdgcn_mfma_f32_32x32x16_bf16(kf, qf[c], s1, 0, 0, 0);
        }
      }
      __builtin_amdgcn_s_setprio(0);

      // causal mask: key(reg) = kb + st*32 + (reg&3) + 8*(reg>>2) + 4*hi
      if (kb + 31 > qw) {
        #pragma unroll
        for (int reg = 0; reg < 16; ++reg) {
          int key = kb + (reg & 3) + 8 * (reg >> 2) + 4 * hi;
          if (key > tq) s0[reg] = -3e38f;
        }
      }
      if (act1 && kb + 63 > qw) {
        #pragma unroll
        for (int reg = 0; reg < 16; ++reg) {
          int key = kb + 32 + (reg & 3) + 8 * (reg >> 2) + 4 * hi;
          if (key > tq) s1[reg] = -3e38f;
        }
      }

      // per-lane max (defer-max: cross-lane only when max grows > THR)
      float pm = s0[0];
      #pragma unroll
      for (int reg = 1; reg < 16; ++reg) pm = fmaxf(pm, s0[reg]);
      if (act1) {
        #pragma unroll
        for (int reg = 0; reg < 16; ++reg) pm = fmaxf(pm, s1[reg]);
      }
      if (__any(pm > m_run + DEFER_THR)) {
        float tm = fmaxf(pm, __shfl_xor(pm, 32));   // pair (lane, lane+32) = same q
        float mn = fmaxf(m_run, tm);
        float f = __builtin_amdgcn_exp2f(m_run - mn);
        m_run = mn;
        #pragma unroll
        for (int i = 0; i < 16; ++i) { o0[i] *= f; o1[i] *= f; }
        l_run *= f;
      }

      // P = exp2(S - m) in place; per-lane partial denominator
      #pragma unroll
      for (int reg = 0; reg < 16; ++reg) {
        s0[reg] = __builtin_amdgcn_exp2f(s0[reg] - m_run);
        l_run += s0[reg];
      }
      if (act1) {
        #pragma unroll
        for (int reg = 0; reg < 16; ++reg) {
          s1[reg] = __builtin_amdgcn_exp2f(s1[reg] - m_run);
          l_run += s1[reg];
        }
      }

      // PV: O^T += V^T·P^T.  B-frag = own P packs (keys 16u+4hi+{0..3,8..11});
      // A-frag reads Vt at the SAME permuted key offsets.
      __builtin_amdgcn_s_setprio(1);
      #pragma unroll
      for (int st = 0; st < 2; ++st) {
        if (st == 1 && !act1) break;
        #pragma unroll
        for (int u = 0; u < 2; ++u) {
          u32x4 pw;
          #pragma unroll
          for (int j = 0; j < 4; ++j) {
            int jr = (4 * u + j) * 2;
            pw[j] = st ? cvt_pk_bf16(s1[jr], s1[jr + 1])
                       : cvt_pk_bf16(s0[jr], s0[jr + 1]);
          }
          bf16x8 pf = __builtin_bit_cast(bf16x8, pw);
          const int keybase = st * 32 + u * 16;
          #pragma unroll
          for (int dt = 0; dt < 2; ++dt) {
            int row = dt * 32 + col;
            int e0 = (row * 64 + keybase + 4 * hi) ^ ((row & 7) << 3);
            int e1 = (row * 64 + keybase + 8 + 4 * hi) ^ ((row & 7) << 3);
            bf16x4 vlo = *(const bf16x4*)(&sV[cur][e0]);
            bf16x4 vhi = *(const bf16x4*)(&sV[cur][e1]);
            bf16x8 vf;
            vf[0] = vlo[0]; vf[1] = vlo[1]; vf[2] = vlo[2]; vf[3] = vlo[3];
            vf[4] = vhi[0]; vf[5] = vhi[1]; vf[6] = vhi[2]; vf[7] = vhi[3];
            if (dt == 0) o0 = __builtin_amdgcn_mfma_f32_32x32x16_bf16(vf, pf, o0, 0, 0, 0);
            else         o1 = __builtin_amdgcn_mfma_f32_32x32x16_bf16(vf, pf, o1, 0, 0, 0);
          }
        }
      }
      __builtin_amdgcn_s_setprio(0);
    }
    __syncthreads();   // next-tile staging landed; buffers swap

    if (it == ntA - 1) {
      // finalize half A, reset state, switch to q-tile B (tile 0 already staged)
      FINAL();
      qw = qtB * 64 + w * 32;
      tq = qw + col;
      #pragma unroll
      for (int c = 0; c < 4; ++c)
        qf[c] = *(const bf16x8*)(Qb + (bhK + tq) * D_ + c * 16 + hi * 8);
      m_run = -3e38f; l_run = 0.f;
      #pragma unroll
      for (int i = 0; i < 16; ++i) { o0[i] = 0.f; o1[i] = 0.f; }
    }
  }
  FINAL();   // half B
}

extern "C" void kernel_launch(void* const* d_in, const int* in_sizes, int n_in,
                              void* d_out, int out_size, void* d_ws, size_t ws_size,
                              hipStream_t stream) {
  const float* x     = (const float*)d_in[0];
  const float* W_in  = (const float*)d_in[1];
  const float* b_in  = (const float*)d_in[2];
  const float* W_out = (const float*)d_in[3];
  const float* b_out = (const float*)d_in[4];
  float* out = (float*)d_out;

  const size_t NE = (size_t)B_ * H_ * T_ * D_;   // 8388608
  u16* Qb    = (u16*)d_ws;
  u16* Kb    = Qb + NE;
  u16* Vb    = Kb + NE;     // row-major V from GEMM1; becomes ybf after vtrans
  u16* xbf   = Vb + NE;     // GEMM1 A-input; becomes Vt after GEMM1
  u16* WtIn  = xbf + (size_t)M_ * C_;
  u16* WtOut = WtIn + (size_t)N3_ * C_;
  float* ctab = (float*)(WtOut + (size_t)C_ * C_);
  float* stab = ctab + T_ * 32;
  u16* Vt  = xbf;   // overlays xbf (dead after GEMM1)
  u16* ybf = Vb;    // overlays Vb  (dead after k_vtrans)

  size_t needed = (size_t)((char*)(stab + T_ * 32) - (char*)d_ws);
  if (ws_size < needed) return;

  k_convert<<<4096, 256, 0, stream>>>(x, xbf, (M_ * C_) / 8);
  k_transpose<<<dim3(N3_ / 64, C_ / 64), 256, 0, stream>>>(W_in, WtIn, C_, N3_);
  k_transpose<<<dim3(C_ / 64, C_ / 64), 256, 0, stream>>>(W_out, WtOut, C_, C_);
  k_rope_table<<<(T_ * 32) / 256, 256, 0, stream>>>(ctab, stab);

  k_gemm<0><<<dim3(N3_ / 128, M_ / 128), 256, 0, stream>>>(
      xbf, WtIn, b_in, nullptr, Qb, Kb, Vb, ctab, stab, M_, N3_, C_);

  k_vtrans<<<dim3(T_ / 64, H_, B_), 256, 0, stream>>>(Vb, Vt);

  k_attn<<<dim3(NKT_ / 2, H_, B_), 128, 0, stream>>>(Qb, Kb, Vt, ybf);

  k_gemm<1><<<dim3(C_ / 128, M_ / 128), 256, 0, stream>>>(
      ybf, WtOut, b_out, out, nullptr, nullptr, nullptr, nullptr, nullptr, M_, C_, C_);
}